// Round 15
// baseline (56.632 us; speedup 1.0000x reference)
//
#include <hip/hip_runtime.h>

// Problem constants (match reference setup)
#define BB     4
#define NW     128
#define HG     512
#define WG     512
#define EDIM   64
#define HIDDEN 768

typedef float f4 __attribute__((ext_vector_type(4)));

// ---------------------------------------------------------------------------
// Single fused kernel — R14 structure + forced 8-waves/SIMD occupancy.
// 2048 blocks = 8 XCDs x 256; lin = b(2)|e5(5)|ht(4); 2 e-planes per block,
// 32-row tile, wave = one 8-row sub-tile. __launch_bounds__(256,8) caps
// VGPR at 64 so all 8 blocks/CU are truly resident (32 waves/CU).
// Phase 2 loads proj fragments per-iteration (L1-hot) to fit the budget.
// Plain f4 stores (NT bypasses L2 write-combining: R8 = -10.5 us).
// ---------------------------------------------------------------------------
__global__ __launch_bounds__(256, 8) void fused_kernel(
    const float* __restrict__ bbox,
    const float* __restrict__ emb,
    const float* __restrict__ proj,
    const int*   __restrict__ ids,
    const int*   __restrict__ stride_p,
    float*       __restrict__ out)
{
    const int t = threadIdx.x;
    // 2048 = 8 XCDs x 256; block i -> XCD i%8 -> contiguous lin chunk.
    const int lin = ((blockIdx.x & 7) << 8) | (blockIdx.x >> 3);
    const int b  = lin >> 9;             // 2 XCDs per batch
    const int e0 = ((lin >> 4) & 31) * 2;
    const int ht = lin & 15;
    const int rlo = ht * 32, rhi = rlo + 32;

    __shared__ unsigned entx[NW];        // w0 | w1<<10 | prio<<20
    __shared__ unsigned enty[NW];        // h0 | h1<<16
    __shared__ int      sid[NW];         // word id per filtered box
    __shared__ float    col0[NW + 1];    // plane e0 values by prio (0=bg)
    __shared__ float    col1[NW + 1];    // plane e0+1
    __shared__ unsigned char sublist[4][NW];
    __shared__ int      subcnt[4];
    __shared__ int      cnt;

    if (t == 0) cnt = 0;
    if (t < 4)  subcnt[t] = 0;
    __syncthreads();

    // ---- Phase 1: box filter for this 32-row tile ----
    if (t < NW) {
        const float s = (float)stride_p[0];
        float4 bv = ((const float4*)bbox)[b * NW + t];
        int w0 = (int)rintf(bv.x / s), h0 = (int)rintf(bv.y / s);
        int w1 = (int)rintf(bv.z / s), h1 = (int)rintf(bv.w / s);
        if (h1 > rlo && h0 < rhi && w1 > w0 && h1 > h0) {
            int i = atomicAdd(&cnt, 1);
            entx[i] = (unsigned)w0 | ((unsigned)w1 << 10) | ((unsigned)(t + 1) << 20);
            enty[i] = (unsigned)h0 | ((unsigned)h1 << 16);
            sid[i]  = ids[b * NW + t];
        }
    }
    __syncthreads();

    const int nc = cnt;
    const int wv = t >> 6, l = t & 63;

    // ---- Phase 1b: bucket entries into per-8-row sub-tile lists ----
    if (t < nc) {
        const unsigned ey = enty[t];
        const int h0 = (int)(ey & 0xFFFFu), h1 = (int)(ey >> 16);
        #pragma unroll
        for (int st = 0; st < 4; ++st) {
            const int srl = rlo + st * 8;
            if (h1 > srl && h0 < srl + 8) {
                int k = atomicAdd(&subcnt[st], 1);
                sublist[st][k] = (unsigned char)t;
            }
        }
    }

    // ---- Phase 2: table entries for BOTH planes (j == nc -> background) ----
    // proj fragments loaded per-iteration (L1-hot) to keep VGPR <= 64.
    const f4* pr0 = (const f4*)(proj + (size_t)e0 * HIDDEN) + l * 3;
    const f4* pr1 = (const f4*)(proj + (size_t)(e0 + 1) * HIDDEN) + l * 3;

    for (int j = wv; j <= nc; j += 4) {
        const int id   = (j == nc) ? 0 : sid[j];
        const int slot = (j == nc) ? 0 : (int)(entx[j] >> 20);
        const f4* er = (const f4*)(emb + (size_t)id * HIDDEN) + l * 3;
        f4 a0 = er[0], a1 = er[1], a2 = er[2];
        f4 p0 = pr0[0], p1 = pr0[1], p2 = pr0[2];
        float v0 = a0.x*p0.x + a0.y*p0.y + a0.z*p0.z + a0.w*p0.w
                 + a1.x*p1.x + a1.y*p1.y + a1.z*p1.z + a1.w*p1.w
                 + a2.x*p2.x + a2.y*p2.y + a2.z*p2.z + a2.w*p2.w;
        p0 = pr1[0]; p1 = pr1[1]; p2 = pr1[2];
        float v1 = a0.x*p0.x + a0.y*p0.y + a0.z*p0.z + a0.w*p0.w
                 + a1.x*p1.x + a1.y*p1.y + a1.z*p1.z + a1.w*p1.w
                 + a2.x*p2.x + a2.y*p2.y + a2.z*p2.z + a2.w*p2.w;
        #pragma unroll
        for (int m = 1; m < 64; m <<= 1) {
            v0 += __shfl_xor(v0, m, 64);
            v1 += __shfl_xor(v1, m, 64);
        }
        if (l == 0) { col0[slot] = v0; col1[slot] = v1; }
    }
    __syncthreads();

    // ---- Phase 3: paint 8 rows per wave; winner once, both planes ----
    float* obase0 = out + ((size_t)(b * EDIM + e0)) * HG * WG;
    float* obase1 = obase0 + (size_t)HG * WG;
    const int p0i = 4 * l, p1i = 256 + 4 * l;

    const float bgs0 = col0[0], bgs1 = col1[0];
    const f4 bgv0 = {bgs0, bgs0, bgs0, bgs0};
    const f4 bgv1 = {bgs1, bgs1, bgs1, bgs1};

    const int ns = subcnt[wv];                        // wave = one sub-tile
    for (int rr = 0; rr < 8; ++rr) {
        const int row = rlo + wv * 8 + rr;            // wave-uniform
        f4* orow0 = (f4*)(obase0 + (size_t)row * WG);
        f4* orow1 = (f4*)(obase1 + (size_t)row * WG);

        if (ns == 0) {                                // bg fast path
            orow0[l]      = bgv0;
            orow0[64 + l] = bgv0;
            orow1[l]      = bgv1;
            orow1[64 + l] = bgv1;
            continue;
        }

        int wn0 = 0, wn1 = 0, wn2 = 0, wn3 = 0;
        int wn4 = 0, wn5 = 0, wn6 = 0, wn7 = 0;
        for (int k = 0; k < ns; ++k) {
            const int i = sublist[wv][k];
            const unsigned ey = enty[i];               // broadcast LDS read
            const int h0 = (int)(ey & 0xFFFFu), h1 = (int)(ey >> 16);
            if (row >= h0 && row < h1) {               // wave-uniform branch
                const unsigned ex = entx[i];
                const int w0 = (int)(ex & 1023u);
                const int w1 = (int)((ex >> 10) & 1023u);
                const int pr = (int)(ex >> 20);
                if (p0i     >= w0 && p0i     < w1 && pr > wn0) wn0 = pr;
                if (p0i + 1 >= w0 && p0i + 1 < w1 && pr > wn1) wn1 = pr;
                if (p0i + 2 >= w0 && p0i + 2 < w1 && pr > wn2) wn2 = pr;
                if (p0i + 3 >= w0 && p0i + 3 < w1 && pr > wn3) wn3 = pr;
                if (p1i     >= w0 && p1i     < w1 && pr > wn4) wn4 = pr;
                if (p1i + 1 >= w0 && p1i + 1 < w1 && pr > wn5) wn5 = pr;
                if (p1i + 2 >= w0 && p1i + 2 < w1 && pr > wn6) wn6 = pr;
                if (p1i + 3 >= w0 && p1i + 3 < w1 && pr > wn7) wn7 = pr;
            }
        }
        f4 u0, u1, w0v, w1v;
        u0.x  = col0[wn0]; u0.y  = col0[wn1]; u0.z  = col0[wn2]; u0.w  = col0[wn3];
        u1.x  = col0[wn4]; u1.y  = col0[wn5]; u1.z  = col0[wn6]; u1.w  = col0[wn7];
        w0v.x = col1[wn0]; w0v.y = col1[wn1]; w0v.z = col1[wn2]; w0v.w = col1[wn3];
        w1v.x = col1[wn4]; w1v.y = col1[wn5]; w1v.z = col1[wn6]; w1v.w = col1[wn7];
        orow0[l]      = u0;
        orow0[64 + l] = u1;
        orow1[l]      = w0v;
        orow1[64 + l] = w1v;
    }
}

// ---------------------------------------------------------------------------
extern "C" void kernel_launch(void* const* d_in, const int* in_sizes, int n_in,
                              void* d_out, int out_size, void* d_ws, size_t ws_size,
                              hipStream_t stream)
{
    // inputs: 0 img (unused), 1 bbox, 2 emb_weight, 3 proj_weight,
    //         4 input_ids, 5 stride
    const float* bbox = (const float*)d_in[1];
    const float* emb  = (const float*)d_in[2];
    const float* proj = (const float*)d_in[3];
    const int*   ids  = (const int*)d_in[4];
    const int*   strd = (const int*)d_in[5];

    float* out = (float*)d_out;

    fused_kernel<<<2048, 256, 0, stream>>>(bbox, emb, proj, ids, strd, out);
}

// Round 16
// 51.097 us; speedup vs baseline: 1.1083x; 1.1083x over previous
//
#include <hip/hip_runtime.h>

// Problem constants (match reference setup)
#define BB     4
#define NW     128
#define HG     512
#define WG     512
#define EDIM   64
#define HIDDEN 768

typedef float f4 __attribute__((ext_vector_type(4)));

// ---------------------------------------------------------------------------
// Single fused kernel — 4 e-planes per block, 16-row tiles, full/partial
// box split per 4-row wave window.
// 2048 blocks = 8 XCDs x 256; lin = b(2)|e4(4)|ht(5). 8 blocks/CU.
// Plain f4 stores (NT bypasses L2 write-combining: R8 = -10.5 us).
//
// Phase 1 : filter this batch's 128 boxes against rows [ht*16, ht*16+16).
// Phase 1b: per 4-row window, split into FULL (covers all 4 rows ->
//           row-invariant winner, computed once per wave) and PARTIAL lists.
// Phase 2 : wave-parallel 768-dots for 4 planes; emb row loaded once per j.
// Phase 3 : winner = full-part (hoisted) + partial per row; gather 4 planes
//           via direct b32 LDS reads; 8 f4 stores per row per wave.
// ---------------------------------------------------------------------------
__global__ __launch_bounds__(256) void fused_kernel(
    const float* __restrict__ bbox,
    const float* __restrict__ emb,
    const float* __restrict__ proj,
    const int*   __restrict__ ids,
    const int*   __restrict__ stride_p,
    float*       __restrict__ out)
{
    const int t = threadIdx.x;
    // 2048 = 8 XCDs x 256; block i -> XCD i%8 -> contiguous lin chunk.
    const int lin = ((blockIdx.x & 7) << 8) | (blockIdx.x >> 3);
    const int b  = lin >> 9;             // 2 XCDs per batch
    const int e0 = ((lin >> 5) & 15) * 4;
    const int ht = lin & 31;
    const int rlo = ht * 16, rhi = rlo + 16;

    __shared__ unsigned entx[NW];        // w0 | w1<<10 | prio<<20
    __shared__ unsigned enty[NW];        // h0 | h1<<16
    __shared__ int      sid[NW];         // word id per filtered box
    __shared__ float    col[4][NW + 1];  // per-plane values by prio (0=bg)
    __shared__ unsigned char subF[4][NW];  // full-cover boxes per 4-row window
    __shared__ unsigned char subP[4][NW];  // partial-cover boxes
    __shared__ int      cntF[4], cntP[4];
    __shared__ int      cnt;

    if (t == 0) cnt = 0;
    if (t < 4)  { cntF[t] = 0; cntP[t] = 0; }
    __syncthreads();

    // ---- Phase 1: box filter for this 16-row tile ----
    if (t < NW) {
        const float s = (float)stride_p[0];
        float4 bv = ((const float4*)bbox)[b * NW + t];
        int w0 = (int)rintf(bv.x / s), h0 = (int)rintf(bv.y / s);
        int w1 = (int)rintf(bv.z / s), h1 = (int)rintf(bv.w / s);
        if (h1 > rlo && h0 < rhi && w1 > w0 && h1 > h0) {
            int i = atomicAdd(&cnt, 1);
            entx[i] = (unsigned)w0 | ((unsigned)w1 << 10) | ((unsigned)(t + 1) << 20);
            enty[i] = (unsigned)h0 | ((unsigned)h1 << 16);
            sid[i]  = ids[b * NW + t];
        }
    }
    __syncthreads();

    const int nc = cnt;
    const int wv = t >> 6, l = t & 63;

    // ---- Phase 1b: full/partial split per 4-row window ----
    if (t < nc) {
        const unsigned ey = enty[t];
        const int h0 = (int)(ey & 0xFFFFu), h1 = (int)(ey >> 16);
        #pragma unroll
        for (int wi = 0; wi < 4; ++wi) {
            const int wr = rlo + wi * 4;
            if (h0 <= wr && h1 >= wr + 4) {              // covers all 4 rows
                int k = atomicAdd(&cntF[wi], 1);
                subF[wi][k] = (unsigned char)t;
            } else if (h1 > wr && h0 < wr + 4) {         // partial overlap
                int k = atomicAdd(&cntP[wi], 1);
                subP[wi][k] = (unsigned char)t;
            }
        }
    }

    // ---- Phase 2: table entries for 4 planes (j == nc -> background) ----
    for (int j = wv; j <= nc; j += 4) {
        const int id   = (j == nc) ? 0 : sid[j];
        const int slot = (j == nc) ? 0 : (int)(entx[j] >> 20);
        const f4* er = (const f4*)(emb + (size_t)id * HIDDEN) + l * 3;
        f4 a0 = er[0], a1 = er[1], a2 = er[2];
        float v[4];
        #pragma unroll
        for (int p = 0; p < 4; ++p) {
            const f4* pr = (const f4*)(proj + (size_t)(e0 + p) * HIDDEN) + l * 3;
            f4 p0 = pr[0], p1 = pr[1], p2 = pr[2];
            v[p] = a0.x*p0.x + a0.y*p0.y + a0.z*p0.z + a0.w*p0.w
                 + a1.x*p1.x + a1.y*p1.y + a1.z*p1.z + a1.w*p1.w
                 + a2.x*p2.x + a2.y*p2.y + a2.z*p2.z + a2.w*p2.w;
        }
        #pragma unroll
        for (int m = 1; m < 64; m <<= 1) {
            v[0] += __shfl_xor(v[0], m, 64);
            v[1] += __shfl_xor(v[1], m, 64);
            v[2] += __shfl_xor(v[2], m, 64);
            v[3] += __shfl_xor(v[3], m, 64);
        }
        if (l == 0) {
            col[0][slot] = v[0]; col[1][slot] = v[1];
            col[2][slot] = v[2]; col[3][slot] = v[3];
        }
    }
    __syncthreads();

    // ---- Phase 3: 4 rows per wave; hoisted full-box winner ----
    const int wrlo = rlo + wv * 4;
    const int nF = cntF[wv], nP = cntP[wv];
    const int p0i = 4 * l, p1i = 256 + 4 * l;
    float* ob = out + ((size_t)(b * EDIM + e0)) * HG * WG;
    const size_t PL = (size_t)HG * WG;

    f4 bgv[4];
    #pragma unroll
    for (int p = 0; p < 4; ++p) {
        const float c = col[p][0];
        bgv[p] = (f4){c, c, c, c};
    }

    // row-invariant winner from full-cover boxes (no row test)
    int f0 = 0, f1 = 0, f2 = 0, f3 = 0, f4_ = 0, f5 = 0, f6 = 0, f7 = 0;
    for (int k = 0; k < nF; ++k) {
        const unsigned ex = entx[subF[wv][k]];
        const int w0 = (int)(ex & 1023u);
        const int w1 = (int)((ex >> 10) & 1023u);
        const int pr = (int)(ex >> 20);
        if (p0i     >= w0 && p0i     < w1 && pr > f0)  f0  = pr;
        if (p0i + 1 >= w0 && p0i + 1 < w1 && pr > f1)  f1  = pr;
        if (p0i + 2 >= w0 && p0i + 2 < w1 && pr > f2)  f2  = pr;
        if (p0i + 3 >= w0 && p0i + 3 < w1 && pr > f3)  f3  = pr;
        if (p1i     >= w0 && p1i     < w1 && pr > f4_) f4_ = pr;
        if (p1i + 1 >= w0 && p1i + 1 < w1 && pr > f5)  f5  = pr;
        if (p1i + 2 >= w0 && p1i + 2 < w1 && pr > f6)  f6  = pr;
        if (p1i + 3 >= w0 && p1i + 3 < w1 && pr > f7)  f7  = pr;
    }

    for (int rr = 0; rr < 4; ++rr) {
        const int row = wrlo + rr;                     // wave-uniform
        f4* orow = (f4*)(ob + (size_t)row * WG);

        if ((nF | nP) == 0) {                          // bg fast path
            #pragma unroll
            for (int p = 0; p < 4; ++p) {
                f4* op = orow + p * (PL / 4);
                op[l]      = bgv[p];
                op[64 + l] = bgv[p];
            }
            continue;
        }

        int wn0 = f0, wn1 = f1, wn2 = f2, wn3 = f3;
        int wn4 = f4_, wn5 = f5, wn6 = f6, wn7 = f7;
        for (int k = 0; k < nP; ++k) {
            const int i = subP[wv][k];
            const unsigned ey = enty[i];               // broadcast LDS read
            const int h0 = (int)(ey & 0xFFFFu), h1 = (int)(ey >> 16);
            if (row >= h0 && row < h1) {               // wave-uniform branch
                const unsigned ex = entx[i];
                const int w0 = (int)(ex & 1023u);
                const int w1 = (int)((ex >> 10) & 1023u);
                const int pr = (int)(ex >> 20);
                if (p0i     >= w0 && p0i     < w1 && pr > wn0) wn0 = pr;
                if (p0i + 1 >= w0 && p0i + 1 < w1 && pr > wn1) wn1 = pr;
                if (p0i + 2 >= w0 && p0i + 2 < w1 && pr > wn2) wn2 = pr;
                if (p0i + 3 >= w0 && p0i + 3 < w1 && pr > wn3) wn3 = pr;
                if (p1i     >= w0 && p1i     < w1 && pr > wn4) wn4 = pr;
                if (p1i + 1 >= w0 && p1i + 1 < w1 && pr > wn5) wn5 = pr;
                if (p1i + 2 >= w0 && p1i + 2 < w1 && pr > wn6) wn6 = pr;
                if (p1i + 3 >= w0 && p1i + 3 < w1 && pr > wn7) wn7 = pr;
            }
        }
        #pragma unroll
        for (int p = 0; p < 4; ++p) {
            f4 u0, u1;
            u0.x = col[p][wn0]; u0.y = col[p][wn1];
            u0.z = col[p][wn2]; u0.w = col[p][wn3];
            u1.x = col[p][wn4]; u1.y = col[p][wn5];
            u1.z = col[p][wn6]; u1.w = col[p][wn7];
            f4* op = orow + p * (PL / 4);
            op[l]      = u0;
            op[64 + l] = u1;
        }
    }
}

// ---------------------------------------------------------------------------
extern "C" void kernel_launch(void* const* d_in, const int* in_sizes, int n_in,
                              void* d_out, int out_size, void* d_ws, size_t ws_size,
                              hipStream_t stream)
{
    // inputs: 0 img (unused), 1 bbox, 2 emb_weight, 3 proj_weight,
    //         4 input_ids, 5 stride
    const float* bbox = (const float*)d_in[1];
    const float* emb  = (const float*)d_in[2];
    const float* proj = (const float*)d_in[3];
    const int*   ids  = (const int*)d_in[4];
    const int*   strd = (const int*)d_in[5];

    float* out = (float*)d_out;

    fused_kernel<<<2048, 256, 0, stream>>>(bbox, emb, proj, ids, strd, out);
}